// Round 4
// baseline (5334.899 us; speedup 1.0000x reference)
//
#include <hip/hip_runtime.h>

#define NN      524288      // nodes
#define NE      2097152     // edges
#define NGRAPH  16384
#define GSZ     32
#define PADR    45
#define F_IN    79
#define F_MID   138
#define F_OUT   128

typedef __attribute__((ext_vector_type(8))) short short8;
typedef __attribute__((ext_vector_type(4))) float f32x4;

__device__ __forceinline__ unsigned short f2b(float f) {
    union { float f; unsigned u; } v; v.f = f;
    unsigned r = v.u + 0x7FFF + ((v.u >> 16) & 1);   // RNE
    return (unsigned short)(r >> 16);
}
__device__ __forceinline__ float b2f(unsigned short u) {
    union { unsigned u; float f; } v; v.u = ((unsigned)u) << 16;
    return v.f;
}

// ---------------- degree count ----------------

__global__ void k_init_cnt(int* __restrict__ cnt) {
    int i = blockIdx.x * 256 + threadIdx.x;
    if (i < NN) cnt[i] = 1;                      // self loop
}

__global__ void k_count(const int* __restrict__ dst, int* __restrict__ cnt) {
    int e = blockIdx.x * 256 + threadIdx.x;
    if (e < NE) atomicAdd(&cnt[dst[e]], 1);
}

// ---------------- degree-balanced permutation (counting sort by degree) ----------------

__global__ void k_zero128(int* __restrict__ hist) {
    hist[threadIdx.x] = 0;                       // 128 ints: [0..63] hist, [64..127] cursor
}

__global__ void k_hist(const int* __restrict__ cnt, int* __restrict__ hist) {
    int i = blockIdx.x * 256 + threadIdx.x;
    if (i < NN) atomicAdd(&hist[min(cnt[i], 63)], 1);
}

__global__ void k_hscan(int* __restrict__ hist) {   // 1 block, 64 threads
    __shared__ int s[64];
    int t = threadIdx.x;
    int v = hist[t];
    s[t] = v;
    __syncthreads();
    for (int off = 1; off < 64; off <<= 1) {
        int u = (t >= off) ? s[t - off] : 0;
        __syncthreads();
        s[t] += u;
        __syncthreads();
    }
    int ex = s[t] - v;                           // exclusive
    hist[t] = ex;
    hist[64 + t] = ex;                           // cursor copy
}

__global__ void k_scatter(const int* __restrict__ cnt, int* __restrict__ hist,
                          int* __restrict__ perm, int* __restrict__ ip,
                          float* __restrict__ dinvp) {
    int i = blockIdx.x * 256 + threadIdx.x;
    if (i < NN) {
        int d = min(cnt[i], 63);
        int pos = atomicAdd(&hist[64 + d], 1);
        perm[pos] = i;
        ip[i] = pos;
        dinvp[pos] = rsqrtf((float)cnt[i]);
    }
}

// ---------------- CSR over permuted rows ----------------

__global__ void k_scan1p(const int* __restrict__ cnt, const int* __restrict__ perm,
                         int* __restrict__ rp, int* __restrict__ bsum) {
    __shared__ int s[256];
    int tid = threadIdx.x;
    size_t base = (size_t)blockIdx.x * 1024 + (size_t)tid * 4;
    int c0 = cnt[perm[base + 0]], c1 = cnt[perm[base + 1]];
    int c2 = cnt[perm[base + 2]], c3 = cnt[perm[base + 3]];
    int tsum = c0 + c1 + c2 + c3;
    s[tid] = tsum;
    __syncthreads();
    for (int off = 1; off < 256; off <<= 1) {
        int t = (tid >= off) ? s[tid - off] : 0;
        __syncthreads();
        s[tid] += t;
        __syncthreads();
    }
    int incl = s[tid];
    int ex = incl - tsum;
    rp[base + 0] = ex;
    rp[base + 1] = ex + c0;
    rp[base + 2] = ex + c0 + c1;
    rp[base + 3] = ex + c0 + c1 + c2;
    if (tid == 255) bsum[blockIdx.x] = incl;
}

__global__ void k_scan2(int* __restrict__ bsum) {
    __shared__ int s[512];
    int tid = threadIdx.x;
    int v = bsum[tid];
    s[tid] = v;
    __syncthreads();
    for (int off = 1; off < 512; off <<= 1) {
        int t = (tid >= off) ? s[tid - off] : 0;
        __syncthreads();
        s[tid] += t;
        __syncthreads();
    }
    bsum[tid] = s[tid] - v;                      // exclusive
}

__global__ void k_scan3(int* __restrict__ rp, const int* __restrict__ bsum,
                        int* __restrict__ cursor) {
    int i = blockIdx.x * 256 + threadIdx.x;
    if (i < NN) {
        int v = rp[i] + bsum[i >> 10];
        rp[i] = v;
        cursor[i] = v;
        if (i == 0) rp[NN] = NN + NE;
    }
}

__global__ void k_fill_self(int* __restrict__ cursor, int* __restrict__ col) {
    int t = blockIdx.x * 256 + threadIdx.x;
    if (t < NN) { int s = atomicAdd(&cursor[t], 1); col[s] = t; }
}

__global__ void k_fill_edges(const int* __restrict__ src, const int* __restrict__ dst,
                             const int* __restrict__ ip,
                             int* __restrict__ cursor, int* __restrict__ col) {
    int e = blockIdx.x * 256 + threadIdx.x;
    if (e < NE) {
        int r = ip[dst[e]], c = ip[src[e]];
        int s = atomicAdd(&cursor[r], 1);
        col[s] = c;
    }
}

// ---------------- weight / bias / input prep ----------------

// WT[c][k] = bf16(W[k][c]), zero-padded, stride LDK
__global__ void k_wconv(const float* __restrict__ W, unsigned short* __restrict__ WT,
                        int Fin, int Fout, int LDK) {
    int c = blockIdx.x;
    int k = threadIdx.x;
    float v = (k < Fin && c < Fout) ? W[(size_t)k * Fout + c] : 0.f;
    WT[(size_t)c * LDK + k] = f2b(v);
}

__global__ void k_bpad3(const float* __restrict__ b1, const float* __restrict__ b2,
                        const float* __restrict__ b3, float* __restrict__ bp) {
    int i = threadIdx.x;
    const float* b = (blockIdx.x == 0) ? b1 : (blockIdx.x == 1) ? b2 : b3;
    bp[blockIdx.x * 144 + i] = (i < F_MID) ? b[i] : 0.f;
}

// Xt[ip[n]][c] = bf16(dinv[n] * x[n][c]), stride 80
__global__ void k_xconv(const float* __restrict__ x, const int* __restrict__ ip,
                        const float* __restrict__ dinvp, unsigned short* __restrict__ Xt) {
    int n = blockIdx.x * 4 + threadIdx.y;
    int c = threadIdx.x;            // 0..79
    int t = ip[n];
    float d = dinvp[t];
    float v = (c < F_IN) ? d * x[(size_t)n * F_IN + c] : 0.f;
    Xt[(size_t)t * 80 + c] = f2b(v);
}

// ---------------- fused layer: gather-aggregate + MFMA GEMM (permuted space) ----------------
// Hin bf16 [N][SIN] rows pre-scaled by dinv; SIN in {80,144} (== 32*KSFULL + 16).
// MODE 0: write bf16 prescaled Hout [N][144];  MODE 1: fp32 padded d_out via perm.
template<int SIN, int NT, int MODE>
__global__ __launch_bounds__(512) void
k_fused(const unsigned short* __restrict__ Hin, const unsigned short* __restrict__ WT,
        const float* __restrict__ bias, void* __restrict__ Yout,
        const int* __restrict__ rp, const int* __restrict__ col,
        const float* __restrict__ dinvp, const int* __restrict__ perm) {
    constexpr int KSFULL = SIN / 32;             // 80->2, 144->4
    constexpr int KSTEPS = KSFULL + 1;           // incl. partial step
    constexpr int WROWS = NT * 16;
    constexpr int ROWB = SIN * 2;                // row bytes (160 / 288)
    constexpr int SWZLIM = ROWB & ~127;          // swizzle only full-128B region
    __shared__ __align__(16) unsigned short Ws[WROWS * SIN];

    const int tid = threadIdx.x;
    // ---- cooperative W^T -> LDS (XOR-swizzled) ----
    constexpr int CH = WROWS * SIN / 8;          // 16B chunks
    for (int i = tid; i < CH; i += 512) {
        int r = i / (SIN / 8), cc = i % (SIN / 8);
        int bo = cc * 16;
        int so = (bo < SWZLIM) ? (bo ^ ((r & 7) << 4)) : bo;
        *(f32x4*)((char*)Ws + (size_t)r * ROWB + so) =
            *(const f32x4*)&WT[(size_t)r * SIN + cc * 8];
    }

    const int wv = tid >> 6, lane = tid & 63;
    const int lrow = lane & 15, kg = lane >> 4;
    const int row = blockIdx.x * 128 + wv * 16 + lrow;

    const int beg = rp[row], end = rp[row + 1];

    // ---- gather-aggregate this row's K-slice in fp32 ----
    float acc[KSTEPS][8];
#pragma unroll
    for (int ks = 0; ks < KSTEPS; ++ks)
#pragma unroll
        for (int e = 0; e < 8; ++e) acc[ks][e] = 0.f;

    for (int s = beg; s < end; ++s) {
        int j = col[s];
        const unsigned short* hj = Hin + (size_t)j * SIN + kg * 8;
#pragma unroll
        for (int ks = 0; ks < KSFULL; ++ks) {
            short8 v = *(const short8*)(hj + ks * 32);
#pragma unroll
            for (int e = 0; e < 8; ++e) acc[ks][e] += b2f((unsigned short)v[e]);
        }
        if (kg < 2) {                            // partial step: cols [32*KSFULL, SIN)
            short8 v = *(const short8*)(hj + KSFULL * 32);
#pragma unroll
            for (int e = 0; e < 8; ++e) acc[KSFULL][e] += b2f((unsigned short)v[e]);
        }
    }

    // ---- to bf16 A fragments ----
    const float di = dinvp[row];
    short8 a[KSTEPS];
#pragma unroll
    for (int ks = 0; ks < KSTEPS; ++ks)
#pragma unroll
        for (int e = 0; e < 8; ++e)
            a[ks][e] = (short)f2b(di * acc[ks][e]);
    if (kg >= 2) {
#pragma unroll
        for (int e = 0; e < 8; ++e) a[KSTEPS - 1][e] = 0;   // zero partial A slice
    }

    __syncthreads();                             // Ws ready

    f32x4 acc2[NT];
#pragma unroll
    for (int n = 0; n < NT; ++n) acc2[n] = (f32x4){0.f, 0.f, 0.f, 0.f};

#pragma unroll
    for (int ks = 0; ks < KSTEPS; ++ks) {
        const int bo = ks * 64 + kg * 16;        // chunk byte offset within W row
#pragma unroll
        for (int n = 0; n < NT; ++n) {
            int r = n * 16 + lrow;
            short8 b;
            if (ks == KSTEPS - 1 && kg >= 2) {
                b = a[KSTEPS - 1];               // zero (A slice is zero -> b irrelevant)
            } else {
                int so = (bo < SWZLIM) ? (bo ^ ((r & 7) << 4)) : bo;
                b = *(const short8*)((const char*)Ws + (size_t)r * ROWB + so);
            }
            acc2[n] = __builtin_amdgcn_mfma_f32_16x16x32_bf16(a[ks], b, acc2[n], 0, 0, 0);
        }
    }

    // ---- epilogue: C/D layout col=lane&15, row=(lane>>4)*4+j ----
    const int t0 = blockIdx.x * 128 + wv * 16 + kg * 4;
    if (MODE == 0) {
        unsigned short* Yp = (unsigned short*)Yout;
        float d4[4];
#pragma unroll
        for (int j = 0; j < 4; ++j) d4[j] = dinvp[t0 + j];
#pragma unroll
        for (int n = 0; n < NT; ++n) {
            int c = n * 16 + lrow;
            float bv = bias[c];
#pragma unroll
            for (int j = 0; j < 4; ++j)
                Yp[(size_t)(t0 + j) * 144 + c] = f2b(d4[j] * (acc2[n][j] + bv));
        }
    } else {
        float* Yo = (float*)Yout;
        int pr[4];
#pragma unroll
        for (int j = 0; j < 4; ++j) pr[j] = perm[t0 + j];
#pragma unroll
        for (int n = 0; n < NT; ++n) {
            int c = n * 16 + lrow;
            float bv = bias[c];
#pragma unroll
            for (int j = 0; j < 4; ++j) {
                size_t o = ((size_t)(pr[j] >> 5) * PADR + (pr[j] & 31)) * F_OUT + c;
                Yo[o] = acc2[n][j] + bv;
            }
        }
    }
}

__global__ void k_padzero(float* __restrict__ out) {
    size_t idx = (size_t)blockIdx.x * 256 + threadIdx.x;
    const size_t total = (size_t)NGRAPH * (PADR - GSZ) * F_OUT;
    if (idx < total) {
        size_t b  = idx / ((PADR - GSZ) * F_OUT);
        int rem   = (int)(idx % ((PADR - GSZ) * F_OUT));
        int r     = GSZ + rem / F_OUT;
        int d     = rem % F_OUT;
        out[((size_t)b * PADR + r) * (size_t)F_OUT + d] = 0.f;
    }
}

// ---------------- launch ----------------

static inline size_t align256(size_t x) { return (x + 255) & ~(size_t)255; }

extern "C" void kernel_launch(void* const* d_in, const int* in_sizes, int n_in,
                              void* d_out, int out_size, void* d_ws, size_t ws_size,
                              hipStream_t stream) {
    const float* x   = (const float*)d_in[0];
    const int* ei    = (const int*)d_in[1];
    const int* src   = ei;            // edge_index[0]
    const int* dst   = ei + NE;       // edge_index[1]
    const float* W1  = (const float*)d_in[2];
    const float* b1  = (const float*)d_in[3];
    const float* W2  = (const float*)d_in[4];
    const float* b2  = (const float*)d_in[5];
    const float* W3  = (const float*)d_in[6];
    const float* b3  = (const float*)d_in[7];
    const float* W4  = (const float*)d_in[8];
    const float* b4  = (const float*)d_in[9];

    // workspace layout
    char* p = (char*)d_ws;
    unsigned short* HA = (unsigned short*)p;  p += align256((size_t)NN * 144 * 2);
    unsigned short* HB = (unsigned short*)p;  p += align256((size_t)NN * 144 * 2);
    int* cnt    = (int*)p;              p += align256((size_t)NN * sizeof(int));
    int* rp     = (int*)p;              p += align256(((size_t)NN + 1) * sizeof(int));
    int* cursor = (int*)p;              p += align256((size_t)NN * sizeof(int));
    int* colix  = (int*)p;              p += align256((size_t)(NN + NE) * sizeof(int));
    float* dinvp= (float*)p;            p += align256((size_t)NN * sizeof(float));
    int* perm   = (int*)p;              p += align256((size_t)NN * sizeof(int));
    int* ip     = (int*)p;              p += align256((size_t)NN * sizeof(int));
    int* hist   = (int*)p;              p += align256(128 * sizeof(int));
    int* bsum   = (int*)p;              p += align256(512 * sizeof(int));
    unsigned short* WT1 = (unsigned short*)p; p += align256(144 * 80 * 2);
    unsigned short* WT2 = (unsigned short*)p; p += align256(144 * 144 * 2);
    unsigned short* WT3 = (unsigned short*)p; p += align256(144 * 144 * 2);
    unsigned short* WT4 = (unsigned short*)p; p += align256(128 * 144 * 2);
    float* bp   = (float*)p;            p += align256(3 * 144 * sizeof(float));
    (void)ws_size; (void)n_in; (void)in_sizes; (void)out_size;

    unsigned short* Xt = (unsigned short*)d_out;   // layer-1 bf16 table in d_out scratch

    // ---- degree count + degree-balanced permutation ----
    k_init_cnt<<<NN / 256, 256, 0, stream>>>(cnt);
    k_count<<<NE / 256, 256, 0, stream>>>(dst, cnt);
    k_zero128<<<1, 128, 0, stream>>>(hist);
    k_hist<<<NN / 256, 256, 0, stream>>>(cnt, hist);
    k_hscan<<<1, 64, 0, stream>>>(hist);
    k_scatter<<<NN / 256, 256, 0, stream>>>(cnt, hist, perm, ip, dinvp);

    // ---- CSR in permuted space ----
    k_scan1p<<<NN / 1024, 256, 0, stream>>>(cnt, perm, rp, bsum);
    k_scan2<<<1, 512, 0, stream>>>(bsum);
    k_scan3<<<NN / 256, 256, 0, stream>>>(rp, bsum, cursor);
    k_fill_self<<<NN / 256, 256, 0, stream>>>(cursor, colix);
    k_fill_edges<<<NE / 256, 256, 0, stream>>>(src, dst, ip, cursor, colix);

    // ---- weights / bias / input prep ----
    k_wconv<<<144, 80, 0, stream>>>(W1, WT1, F_IN, F_MID, 80);
    k_wconv<<<144, 144, 0, stream>>>(W2, WT2, F_MID, F_MID, 144);
    k_wconv<<<144, 144, 0, stream>>>(W3, WT3, F_MID, F_MID, 144);
    k_wconv<<<128, 144, 0, stream>>>(W4, WT4, F_MID, F_OUT, 144);
    k_bpad3<<<3, 144, 0, stream>>>(b1, b2, b3, bp);
    {
        dim3 b(80, 4);
        k_xconv<<<NN / 4, b, 0, stream>>>(x, ip, dinvp, Xt);
    }

    const int blocks = NN / 128;   // 4096

    // layer 1: Xt[80] -> HB[144]
    k_fused<80, 9, 0><<<blocks, 512, 0, stream>>>(Xt, WT1, bp, HB, rp, colix, dinvp, perm);
    // layer 2: HB -> HA
    k_fused<144, 9, 0><<<blocks, 512, 0, stream>>>(HB, WT2, bp + 144, HA, rp, colix, dinvp, perm);
    // layer 3: HA -> HB
    k_fused<144, 9, 0><<<blocks, 512, 0, stream>>>(HA, WT3, bp + 288, HB, rp, colix, dinvp, perm);
    // layer 4: HB -> padded fp32 d_out (scatter via perm)
    k_fused<144, 8, 1><<<blocks, 512, 0, stream>>>(HB, WT4, b4, d_out, rp, colix, dinvp, perm);
    // zero pad rows
    {
        size_t total = (size_t)NGRAPH * (PADR - GSZ) * F_OUT;
        k_padzero<<<(unsigned)((total + 255) / 256), 256, 0, stream>>>((float*)d_out);
    }
}

// Round 5
// 1139.719 us; speedup vs baseline: 4.6809x; 4.6809x over previous
//
#include <hip/hip_runtime.h>

#define NN      524288      // nodes
#define NE      2097152     // edges
#define NGRAPH  16384
#define GSZ     32
#define PADR    45
#define F_IN    79
#define F_MID   138
#define F_OUT   128

#define NSTR    256         // cursor stripes for counting sort

typedef __attribute__((ext_vector_type(8))) short short8;
typedef __attribute__((ext_vector_type(4))) float f32x4;

__device__ __forceinline__ unsigned short f2b(float f) {
    union { float f; unsigned u; } v; v.f = f;
    unsigned r = v.u + 0x7FFF + ((v.u >> 16) & 1);   // RNE
    return (unsigned short)(r >> 16);
}
__device__ __forceinline__ float b2f(unsigned short u) {
    union { unsigned u; float f; } v; v.u = ((unsigned)u) << 16;
    return v.f;
}

// ---------------- degree count ----------------

__global__ void k_init_cnt(int* __restrict__ cnt) {
    int i = blockIdx.x * 256 + threadIdx.x;
    if (i < NN) cnt[i] = 1;                      // self loop
}

__global__ void k_count(const int* __restrict__ dst, int* __restrict__ cnt) {
    int e = blockIdx.x * 256 + threadIdx.x;
    if (e < NE) atomicAdd(&cnt[dst[e]], 1);
}

// ---------------- degree-balanced permutation (striped counting sort) ----------------

__global__ void k_zero_hist(int* __restrict__ hist2) {
    int i = blockIdx.x * 256 + threadIdx.x;      // NSTR*64 entries
    hist2[i] = 0;
}

// counts per (stripe, degree); stripe = blockIdx & 255 (nodes grouped 256/block)
__global__ void k_hist2(const int* __restrict__ cnt, int* __restrict__ hist2) {
    int i = blockIdx.x * 256 + threadIdx.x;
    if (i < NN) {
        int d = min(cnt[i], 63);
        atomicAdd(&hist2[(blockIdx.x & (NSTR - 1)) * 64 + d], 1);
    }
}

// exclusive scan over rank order (deg-major, stripe-minor); bases -> cur
__global__ void k_sscan(const int* __restrict__ hist2, int* __restrict__ cur) {
    __shared__ int s[256];
    int t = threadIdx.x;                         // thread t owns ranks [t*64, t*64+64)
    int sum = 0;
    for (int k = 0; k < 64; ++k) {
        int r = t * 64 + k;
        int d = r >> 8, stripe = r & (NSTR - 1);
        sum += hist2[stripe * 64 + d];
    }
    s[t] = sum;
    __syncthreads();
    for (int off = 1; off < 256; off <<= 1) {
        int u = (t >= off) ? s[t - off] : 0;
        __syncthreads();
        s[t] += u;
        __syncthreads();
    }
    int run = s[t] - sum;                        // exclusive base for this thread's span
    for (int k = 0; k < 64; ++k) {
        int r = t * 64 + k;
        int d = r >> 8, stripe = r & (NSTR - 1);
        cur[stripe * 64 + d] = run;
        run += hist2[stripe * 64 + d];
    }
}

__global__ void k_scatter2(const int* __restrict__ cnt, int* __restrict__ cur,
                           int* __restrict__ perm, int* __restrict__ ip,
                           float* __restrict__ dinvp) {
    int i = blockIdx.x * 256 + threadIdx.x;
    if (i < NN) {
        int d = min(cnt[i], 63);
        int pos = atomicAdd(&cur[(blockIdx.x & (NSTR - 1)) * 64 + d], 1);
        perm[pos] = i;
        ip[i] = pos;
        dinvp[pos] = rsqrtf((float)cnt[i]);
    }
}

// ---------------- CSR over permuted rows ----------------

__global__ void k_scan1p(const int* __restrict__ cnt, const int* __restrict__ perm,
                         int* __restrict__ rp, int* __restrict__ bsum) {
    __shared__ int s[256];
    int tid = threadIdx.x;
    size_t base = (size_t)blockIdx.x * 1024 + (size_t)tid * 4;
    int c0 = cnt[perm[base + 0]], c1 = cnt[perm[base + 1]];
    int c2 = cnt[perm[base + 2]], c3 = cnt[perm[base + 3]];
    int tsum = c0 + c1 + c2 + c3;
    s[tid] = tsum;
    __syncthreads();
    for (int off = 1; off < 256; off <<= 1) {
        int t = (tid >= off) ? s[tid - off] : 0;
        __syncthreads();
        s[tid] += t;
        __syncthreads();
    }
    int incl = s[tid];
    int ex = incl - tsum;
    rp[base + 0] = ex;
    rp[base + 1] = ex + c0;
    rp[base + 2] = ex + c0 + c1;
    rp[base + 3] = ex + c0 + c1 + c2;
    if (tid == 255) bsum[blockIdx.x] = incl;
}

__global__ void k_scan2(int* __restrict__ bsum) {
    __shared__ int s[512];
    int tid = threadIdx.x;
    int v = bsum[tid];
    s[tid] = v;
    __syncthreads();
    for (int off = 1; off < 512; off <<= 1) {
        int t = (tid >= off) ? s[tid - off] : 0;
        __syncthreads();
        s[tid] += t;
        __syncthreads();
    }
    bsum[tid] = s[tid] - v;                      // exclusive
}

__global__ void k_scan3(int* __restrict__ rp, const int* __restrict__ bsum,
                        int* __restrict__ cursor) {
    int i = blockIdx.x * 256 + threadIdx.x;
    if (i < NN) {
        int v = rp[i] + bsum[i >> 10];
        rp[i] = v;
        cursor[i] = v;
        if (i == 0) rp[NN] = NN + NE;
    }
}

__global__ void k_fill_self(int* __restrict__ cursor, int* __restrict__ col) {
    int t = blockIdx.x * 256 + threadIdx.x;
    if (t < NN) { int s = atomicAdd(&cursor[t], 1); col[s] = t; }
}

__global__ void k_fill_edges(const int* __restrict__ src, const int* __restrict__ dst,
                             const int* __restrict__ ip,
                             int* __restrict__ cursor, int* __restrict__ col) {
    int e = blockIdx.x * 256 + threadIdx.x;
    if (e < NE) {
        int r = ip[dst[e]], c = ip[src[e]];
        int s = atomicAdd(&cursor[r], 1);
        col[s] = c;
    }
}

// ---------------- weight / bias / input prep ----------------

__global__ void k_wconv(const float* __restrict__ W, unsigned short* __restrict__ WT,
                        int Fin, int Fout, int LDK) {
    int c = blockIdx.x;
    int k = threadIdx.x;
    float v = (k < Fin && c < Fout) ? W[(size_t)k * Fout + c] : 0.f;
    WT[(size_t)c * LDK + k] = f2b(v);
}

__global__ void k_bpad3(const float* __restrict__ b1, const float* __restrict__ b2,
                        const float* __restrict__ b3, float* __restrict__ bp) {
    int i = threadIdx.x;
    const float* b = (blockIdx.x == 0) ? b1 : (blockIdx.x == 1) ? b2 : b3;
    bp[blockIdx.x * 144 + i] = (i < F_MID) ? b[i] : 0.f;
}

// Xt[ip[n]][c] = bf16(dinv[n] * x[n][c]), stride 80
__global__ void k_xconv(const float* __restrict__ x, const int* __restrict__ ip,
                        const float* __restrict__ dinvp, unsigned short* __restrict__ Xt) {
    int n = blockIdx.x * 4 + threadIdx.y;
    int c = threadIdx.x;            // 0..79
    int t = ip[n];
    float d = dinvp[t];
    float v = (c < F_IN) ? d * x[(size_t)n * F_IN + c] : 0.f;
    Xt[(size_t)t * 80 + c] = f2b(v);
}

// ---------------- fused layer: gather-aggregate + MFMA GEMM (permuted space) ----------------
template<int SIN, int NT, int MODE>
__global__ __launch_bounds__(512) void
k_fused(const unsigned short* __restrict__ Hin, const unsigned short* __restrict__ WT,
        const float* __restrict__ bias, void* __restrict__ Yout,
        const int* __restrict__ rp, const int* __restrict__ col,
        const float* __restrict__ dinvp, const int* __restrict__ perm) {
    constexpr int KSFULL = SIN / 32;             // 80->2, 144->4
    constexpr int KSTEPS = KSFULL + 1;           // incl. partial step
    constexpr int WROWS = NT * 16;
    constexpr int ROWB = SIN * 2;                // row bytes (160 / 288)
    constexpr int SWZLIM = ROWB & ~127;          // swizzle only full-128B region
    __shared__ __align__(16) unsigned short Ws[WROWS * SIN];

    const int tid = threadIdx.x;
    constexpr int CH = WROWS * SIN / 8;          // 16B chunks
    for (int i = tid; i < CH; i += 512) {
        int r = i / (SIN / 8), cc = i % (SIN / 8);
        int bo = cc * 16;
        int so = (bo < SWZLIM) ? (bo ^ ((r & 7) << 4)) : bo;
        *(f32x4*)((char*)Ws + (size_t)r * ROWB + so) =
            *(const f32x4*)&WT[(size_t)r * SIN + cc * 8];
    }

    const int wv = tid >> 6, lane = tid & 63;
    const int lrow = lane & 15, kg = lane >> 4;
    const int row = blockIdx.x * 128 + wv * 16 + lrow;

    const int beg = rp[row], end = rp[row + 1];

    float acc[KSTEPS][8];
#pragma unroll
    for (int ks = 0; ks < KSTEPS; ++ks)
#pragma unroll
        for (int e = 0; e < 8; ++e) acc[ks][e] = 0.f;

    for (int s = beg; s < end; ++s) {
        int j = col[s];
        const unsigned short* hj = Hin + (size_t)j * SIN + kg * 8;
#pragma unroll
        for (int ks = 0; ks < KSFULL; ++ks) {
            short8 v = *(const short8*)(hj + ks * 32);
#pragma unroll
            for (int e = 0; e < 8; ++e) acc[ks][e] += b2f((unsigned short)v[e]);
        }
        if (kg < 2) {                            // partial step: cols [32*KSFULL, SIN)
            short8 v = *(const short8*)(hj + KSFULL * 32);
#pragma unroll
            for (int e = 0; e < 8; ++e) acc[KSFULL][e] += b2f((unsigned short)v[e]);
        }
    }

    const float di = dinvp[row];
    short8 a[KSTEPS];
#pragma unroll
    for (int ks = 0; ks < KSTEPS; ++ks)
#pragma unroll
        for (int e = 0; e < 8; ++e)
            a[ks][e] = (short)f2b(di * acc[ks][e]);
    if (kg >= 2) {
#pragma unroll
        for (int e = 0; e < 8; ++e) a[KSTEPS - 1][e] = 0;
    }

    __syncthreads();                             // Ws ready

    f32x4 acc2[NT];
#pragma unroll
    for (int n = 0; n < NT; ++n) acc2[n] = (f32x4){0.f, 0.f, 0.f, 0.f};

#pragma unroll
    for (int ks = 0; ks < KSTEPS; ++ks) {
        const int bo = ks * 64 + kg * 16;
#pragma unroll
        for (int n = 0; n < NT; ++n) {
            int r = n * 16 + lrow;
            short8 b;
            if (ks == KSTEPS - 1 && kg >= 2) {
                b = a[KSTEPS - 1];
            } else {
                int so = (bo < SWZLIM) ? (bo ^ ((r & 7) << 4)) : bo;
                b = *(const short8*)((const char*)Ws + (size_t)r * ROWB + so);
            }
            acc2[n] = __builtin_amdgcn_mfma_f32_16x16x32_bf16(a[ks], b, acc2[n], 0, 0, 0);
        }
    }

    const int t0 = blockIdx.x * 128 + wv * 16 + kg * 4;
    if (MODE == 0) {
        unsigned short* Yp = (unsigned short*)Yout;
        float d4[4];
#pragma unroll
        for (int j = 0; j < 4; ++j) d4[j] = dinvp[t0 + j];
#pragma unroll
        for (int n = 0; n < NT; ++n) {
            int c = n * 16 + lrow;
            float bv = bias[c];
#pragma unroll
            for (int j = 0; j < 4; ++j)
                Yp[(size_t)(t0 + j) * 144 + c] = f2b(d4[j] * (acc2[n][j] + bv));
        }
    } else {
        float* Yo = (float*)Yout;
        int pr[4];
#pragma unroll
        for (int j = 0; j < 4; ++j) pr[j] = perm[t0 + j];
#pragma unroll
        for (int n = 0; n < NT; ++n) {
            int c = n * 16 + lrow;
            float bv = bias[c];
#pragma unroll
            for (int j = 0; j < 4; ++j) {
                size_t o = ((size_t)(pr[j] >> 5) * PADR + (pr[j] & 31)) * F_OUT + c;
                Yo[o] = acc2[n][j] + bv;
            }
        }
    }
}

__global__ void k_padzero(float* __restrict__ out) {
    size_t idx = (size_t)blockIdx.x * 256 + threadIdx.x;
    const size_t total = (size_t)NGRAPH * (PADR - GSZ) * F_OUT;
    if (idx < total) {
        size_t b  = idx / ((PADR - GSZ) * F_OUT);
        int rem   = (int)(idx % ((PADR - GSZ) * F_OUT));
        int r     = GSZ + rem / F_OUT;
        int d     = rem % F_OUT;
        out[((size_t)b * PADR + r) * (size_t)F_OUT + d] = 0.f;
    }
}

// ---------------- launch ----------------

static inline size_t align256(size_t x) { return (x + 255) & ~(size_t)255; }

extern "C" void kernel_launch(void* const* d_in, const int* in_sizes, int n_in,
                              void* d_out, int out_size, void* d_ws, size_t ws_size,
                              hipStream_t stream) {
    const float* x   = (const float*)d_in[0];
    const int* ei    = (const int*)d_in[1];
    const int* src   = ei;            // edge_index[0]
    const int* dst   = ei + NE;       // edge_index[1]
    const float* W1  = (const float*)d_in[2];
    const float* b1  = (const float*)d_in[3];
    const float* W2  = (const float*)d_in[4];
    const float* b2  = (const float*)d_in[5];
    const float* W3  = (const float*)d_in[6];
    const float* b3  = (const float*)d_in[7];
    const float* W4  = (const float*)d_in[8];
    const float* b4  = (const float*)d_in[9];

    // workspace layout
    char* p = (char*)d_ws;
    unsigned short* HA = (unsigned short*)p;  p += align256((size_t)NN * 144 * 2);
    unsigned short* HB = (unsigned short*)p;  p += align256((size_t)NN * 144 * 2);
    int* cnt    = (int*)p;              p += align256((size_t)NN * sizeof(int));
    int* rp     = (int*)p;              p += align256(((size_t)NN + 1) * sizeof(int));
    int* cursor = (int*)p;              p += align256((size_t)NN * sizeof(int));
    int* colix  = (int*)p;              p += align256((size_t)(NN + NE) * sizeof(int));
    float* dinvp= (float*)p;            p += align256((size_t)NN * sizeof(float));
    int* perm   = (int*)p;              p += align256((size_t)NN * sizeof(int));
    int* ip     = (int*)p;              p += align256((size_t)NN * sizeof(int));
    int* hist2  = (int*)p;              p += align256((size_t)NSTR * 64 * sizeof(int));
    int* cur    = (int*)p;              p += align256((size_t)NSTR * 64 * sizeof(int));
    int* bsum   = (int*)p;              p += align256(512 * sizeof(int));
    unsigned short* WT1 = (unsigned short*)p; p += align256(144 * 80 * 2);
    unsigned short* WT2 = (unsigned short*)p; p += align256(144 * 144 * 2);
    unsigned short* WT3 = (unsigned short*)p; p += align256(144 * 144 * 2);
    unsigned short* WT4 = (unsigned short*)p; p += align256(128 * 144 * 2);
    float* bp   = (float*)p;            p += align256(3 * 144 * sizeof(float));
    (void)ws_size; (void)n_in; (void)in_sizes; (void)out_size;

    unsigned short* Xt = (unsigned short*)d_out;   // layer-1 bf16 table in d_out scratch

    // ---- degree count + striped counting sort ----
    k_init_cnt<<<NN / 256, 256, 0, stream>>>(cnt);
    k_count<<<NE / 256, 256, 0, stream>>>(dst, cnt);
    k_zero_hist<<<NSTR * 64 / 256, 256, 0, stream>>>(hist2);
    k_hist2<<<NN / 256, 256, 0, stream>>>(cnt, hist2);
    k_sscan<<<1, 256, 0, stream>>>(hist2, cur);
    k_scatter2<<<NN / 256, 256, 0, stream>>>(cnt, cur, perm, ip, dinvp);

    // ---- CSR in permuted space ----
    k_scan1p<<<NN / 1024, 256, 0, stream>>>(cnt, perm, rp, bsum);
    k_scan2<<<1, 512, 0, stream>>>(bsum);
    k_scan3<<<NN / 256, 256, 0, stream>>>(rp, bsum, cursor);
    k_fill_self<<<NN / 256, 256, 0, stream>>>(cursor, colix);
    k_fill_edges<<<NE / 256, 256, 0, stream>>>(src, dst, ip, cursor, colix);

    // ---- weights / bias / input prep ----
    k_wconv<<<144, 80, 0, stream>>>(W1, WT1, F_IN, F_MID, 80);
    k_wconv<<<144, 144, 0, stream>>>(W2, WT2, F_MID, F_MID, 144);
    k_wconv<<<144, 144, 0, stream>>>(W3, WT3, F_MID, F_MID, 144);
    k_wconv<<<128, 144, 0, stream>>>(W4, WT4, F_MID, F_OUT, 144);
    k_bpad3<<<3, 144, 0, stream>>>(b1, b2, b3, bp);
    {
        dim3 b(80, 4);
        k_xconv<<<NN / 4, b, 0, stream>>>(x, ip, dinvp, Xt);
    }

    const int blocks = NN / 128;   // 4096

    // layer 1: Xt[80] -> HB[144]
    k_fused<80, 9, 0><<<blocks, 512, 0, stream>>>(Xt, WT1, bp, HB, rp, colix, dinvp, perm);
    // layer 2: HB -> HA
    k_fused<144, 9, 0><<<blocks, 512, 0, stream>>>(HB, WT2, bp + 144, HA, rp, colix, dinvp, perm);
    // layer 3: HA -> HB
    k_fused<144, 9, 0><<<blocks, 512, 0, stream>>>(HA, WT3, bp + 288, HB, rp, colix, dinvp, perm);
    // layer 4: HB -> padded fp32 d_out (scatter via perm)
    k_fused<144, 8, 1><<<blocks, 512, 0, stream>>>(HB, WT4, b4, d_out, rp, colix, dinvp, perm);
    // zero pad rows
    {
        size_t total = (size_t)NGRAPH * (PADR - GSZ) * F_OUT;
        k_padzero<<<(unsigned)((total + 255) / 256), 256, 0, stream>>>((float*)d_out);
    }
}